// Round 6
// baseline (925.516 us; speedup 1.0000x reference)
//
#include <hip/hip_runtime.h>
#include <hip/hip_bf16.h>

#define VOCAB  50257
#define KCTX   8
#define EMBED  64
#define HIDDEN 1024
#define BATCH  256

typedef __attribute__((ext_vector_type(8))) short bf16x8;
typedef __attribute__((ext_vector_type(4))) float f32x4;

static __device__ __forceinline__ unsigned short f2bf(float f) {
  union { float f; unsigned u; } un; un.f = f;
  unsigned r = un.u + 0x7FFFu + ((un.u >> 16) & 1u);   // RNE
  return (unsigned short)(r >> 16);
}

static __device__ __forceinline__ float silu_f(float x) { return x / (1.f + __expf(-x)); }

// ---------------------------------------------------------------------------
// Kernel 1: early-exit one-hot scan.  One wave per (b,k) row; 8KB chunks.
// Row stride 50257 floats is ODD -> scalar dword loads only.
// ---------------------------------------------------------------------------
__global__ __launch_bounds__(256) void k_scan(const float* __restrict__ ctx,
                                              int* __restrict__ idx,
                                              float* __restrict__ val) {
  int wid = blockIdx.x * 4 + (threadIdx.x >> 6);   // row id, 2048 total
  int lane = threadIdx.x & 63;
  const float* row = ctx + (size_t)wid * VOCAB;
  bool found = false;
  int base = 0;
  for (; base + 2048 <= VOCAB; base += 2048) {
    float v[32];
    #pragma unroll
    for (int u = 0; u < 32; ++u) v[u] = row[base + lane + 64 * u];
    bool hit = false;
    #pragma unroll
    for (int u = 0; u < 32; ++u) hit = hit || (v[u] != 0.f);
    if (hit) {
      #pragma unroll
      for (int u = 0; u < 32; ++u)
        if (v[u] != 0.f) { idx[wid] = base + lane + 64 * u; val[wid] = v[u]; }
    }
    if (__any(hit)) { found = true; break; }
  }
  if (!found) {                                    // tail: 1105 elems, guarded
    #pragma unroll
    for (int u = 0; u < 18; ++u) {
      int i = base + lane + 64 * u;
      float v = (i < VOCAB) ? row[i] : 0.f;
      if (v != 0.f) { idx[wid] = i; val[wid] = v; }
    }
  }
}

// ---------------------------------------------------------------------------
// Kernel 2: fused gather + L1 + SiLU + L2 + SiLU -> x2 (bf16).  2 rows/block,
// 128 blocks: halves weight re-read traffic vs 1 row/block (768 MB L2-side).
// ---------------------------------------------------------------------------
__global__ __launch_bounds__(256) void k_mlp(const int* __restrict__ idx,
                                             const float* __restrict__ val,
                                             const float* __restrict__ embed_w,
                                             const float* __restrict__ W1,
                                             const float* __restrict__ b1,
                                             const float* __restrict__ W2,
                                             const float* __restrict__ b2,
                                             unsigned short* __restrict__ x2) {
  __shared__ float x0[2][512];
  __shared__ float x1[2][1024];
  int r0 = blockIdx.x * 2;
  int t = threadIdx.x;

  for (int e = t; e < 2 * 512; e += 256) {
    int rr = e >> 9, j = e & 511;
    int ks = j >> 6, em = j & 63;
    int bk = (r0 + rr) * KCTX + ks;
    x0[rr][j] = embed_w[idx[bk] * EMBED + em] * val[bk];
  }
  __syncthreads();

  {
    float4 acc0 = ((const float4*)b1)[t];
    float4 acc1 = acc0;
    #pragma unroll 4
    for (int j = 0; j < 512; ++j) {
      float4 w = ((const float4*)(W1 + (size_t)j * HIDDEN))[t];
      float xa = x0[0][j], xb = x0[1][j];
      acc0.x = fmaf(xa, w.x, acc0.x); acc0.y = fmaf(xa, w.y, acc0.y);
      acc0.z = fmaf(xa, w.z, acc0.z); acc0.w = fmaf(xa, w.w, acc0.w);
      acc1.x = fmaf(xb, w.x, acc1.x); acc1.y = fmaf(xb, w.y, acc1.y);
      acc1.z = fmaf(xb, w.z, acc1.z); acc1.w = fmaf(xb, w.w, acc1.w);
    }
    float4 s0 = {silu_f(acc0.x), silu_f(acc0.y), silu_f(acc0.z), silu_f(acc0.w)};
    float4 s1 = {silu_f(acc1.x), silu_f(acc1.y), silu_f(acc1.z), silu_f(acc1.w)};
    *(float4*)&x1[0][4 * t] = s0;
    *(float4*)&x1[1][4 * t] = s1;
  }
  __syncthreads();

  {
    float4 acc0 = ((const float4*)b2)[t];
    float4 acc1 = acc0;
    #pragma unroll 4
    for (int j = 0; j < 1024; ++j) {
      float4 w = ((const float4*)(W2 + (size_t)j * HIDDEN))[t];
      float xa = x1[0][j], xb = x1[1][j];
      acc0.x = fmaf(xa, w.x, acc0.x); acc0.y = fmaf(xa, w.y, acc0.y);
      acc0.z = fmaf(xa, w.z, acc0.z); acc0.w = fmaf(xa, w.w, acc0.w);
      acc1.x = fmaf(xb, w.x, acc1.x); acc1.y = fmaf(xb, w.y, acc1.y);
      acc1.z = fmaf(xb, w.z, acc1.z); acc1.w = fmaf(xb, w.w, acc1.w);
    }
    ushort4 o0 = {f2bf(silu_f(acc0.x)), f2bf(silu_f(acc0.y)),
                  f2bf(silu_f(acc0.z)), f2bf(silu_f(acc0.w))};
    ushort4 o1 = {f2bf(silu_f(acc1.x)), f2bf(silu_f(acc1.y)),
                  f2bf(silu_f(acc1.z)), f2bf(silu_f(acc1.w))};
    *(ushort4*)(x2 + (size_t)(r0 + 0) * HIDDEN + 4 * t) = o0;
    *(ushort4*)(x2 + (size_t)(r0 + 1) * HIDDEN + 4 * t) = o1;
  }
}

// ---------------------------------------------------------------------------
// Kernel 3: layer 3 via bf16 MFMA, 256 rows x 64 cols per block.
// W3 k-tile staged to LDS as TRANSPOSED bf16 [64 col][32 k], double-buffered,
// XOR-swizzled (bits[6:4] ^= ((col>>1)^(col>>4))&7): B-frag ds_read_b128 and
// packed ds_write_b32 staging are both 2-way (free).  Per k-step per wave:
// 4 ds_read_b128 + 16 MFMA, zero per-step converts (was 32 b32 + 32 cvt).
// ---------------------------------------------------------------------------
static __device__ __forceinline__ int swzoff(int col, int kbyte) {
  int g = ((col >> 1) ^ (col >> 4)) & 7;
  return (col * 64 + kbyte) ^ (g << 4);
}

__global__ __launch_bounds__(256, 4) void k_l3(const short* __restrict__ x2,
                                               const float* __restrict__ W3,
                                               const float* __restrict__ b3,
                                               float* __restrict__ out) {
  __shared__ char bs[2][4096];                     // 2 x (64 col x 32 k) bf16
  int tid = threadIdx.x;
  int wave = tid >> 6, lane = tid & 63;
  int l15 = lane & 15, l4 = lane >> 4;
  int col0 = blockIdx.x * 64;
  int wrow = wave * 64;

  f32x4 acc[4][4];
  #pragma unroll
  for (int mi = 0; mi < 4; ++mi)
    #pragma unroll
    for (int ni = 0; ni < 4; ++ni)
      acc[mi][ni] = (f32x4){0.f, 0.f, 0.f, 0.f};

  const short* aP0 = x2 + (size_t)(wrow +  0 + l15) * HIDDEN + l4 * 8;
  const short* aP1 = x2 + (size_t)(wrow + 16 + l15) * HIDDEN + l4 * 8;
  const short* aP2 = x2 + (size_t)(wrow + 32 + l15) * HIDDEN + l4 * 8;
  const short* aP3 = x2 + (size_t)(wrow + 48 + l15) * HIDDEN + l4 * 8;

  if (col0 + 64 <= VOCAB) {
    // staging assignment: thread t -> k-pair kp = t>>4 (k = 2kp, 2kp+1),
    // cols c4 = (t&15)*4 .. +3.  Global rows are coalesced per 16 threads.
    int kp = tid >> 4;
    int c4 = (tid & 15) * 4;
    const float* g0 = W3 + (size_t)(2 * kp + 0) * VOCAB + col0 + c4;
    const float* g1 = W3 + (size_t)(2 * kp + 1) * VOCAB + col0 + c4;
    // precomputed swizzled write offsets (4 dwords)
    int wo0 = swzoff(c4 + 0, kp * 4), wo1 = swzoff(c4 + 1, kp * 4);
    int wo2 = swzoff(c4 + 2, kp * 4), wo3 = swzoff(c4 + 3, kp * 4);
    // precomputed swizzled read offsets (4 x b128)
    int ro0 = swzoff( 0 + l15, l4 * 16), ro1 = swzoff(16 + l15, l4 * 16);
    int ro2 = swzoff(32 + l15, l4 * 16), ro3 = swzoff(48 + l15, l4 * 16);

    {                                              // prologue: stage tile 0
      float r0[4], r1[4];
      #pragma unroll
      for (int u = 0; u < 4; ++u) { r0[u] = g0[u]; r1[u] = g1[u]; }
      unsigned* b = (unsigned*)bs[0];
      *(unsigned*)(bs[0] + wo0) = (unsigned)f2bf(r0[0]) | ((unsigned)f2bf(r1[0]) << 16);
      *(unsigned*)(bs[0] + wo1) = (unsigned)f2bf(r0[1]) | ((unsigned)f2bf(r1[1]) << 16);
      *(unsigned*)(bs[0] + wo2) = (unsigned)f2bf(r0[2]) | ((unsigned)f2bf(r1[2]) << 16);
      *(unsigned*)(bs[0] + wo3) = (unsigned)f2bf(r0[3]) | ((unsigned)f2bf(r1[3]) << 16);
      (void)b;
    }
    __syncthreads();

    for (int it = 0; it < 32; ++it) {
      int cur = it & 1;
      // T14: issue next-tile global loads early
      float r0[4], r1[4];
      bool more = (it + 1) < 32;
      if (more) {
        const float* h0 = g0 + (size_t)(it + 1) * 32 * VOCAB;
        const float* h1 = g1 + (size_t)(it + 1) * 32 * VOCAB;
        #pragma unroll
        for (int u = 0; u < 4; ++u) { r0[u] = h0[u]; r1[u] = h1[u]; }
      }
      // A fragments (x2 is L2-resident)
      int k0 = it * 32;
      bf16x8 a0 = *reinterpret_cast<const bf16x8*>(aP0 + k0);
      bf16x8 a1 = *reinterpret_cast<const bf16x8*>(aP1 + k0);
      bf16x8 a2 = *reinterpret_cast<const bf16x8*>(aP2 + k0);
      bf16x8 a3 = *reinterpret_cast<const bf16x8*>(aP3 + k0);
      // B fragments: one ds_read_b128 per ni
      const char* lb = bs[cur];
      bf16x8 b0 = *reinterpret_cast<const bf16x8*>(lb + ro0);
      bf16x8 b1 = *reinterpret_cast<const bf16x8*>(lb + ro1);
      bf16x8 b2 = *reinterpret_cast<const bf16x8*>(lb + ro2);
      bf16x8 b3v = *reinterpret_cast<const bf16x8*>(lb + ro3);
      acc[0][0] = __builtin_amdgcn_mfma_f32_16x16x32_bf16(a0, b0, acc[0][0], 0, 0, 0);
      acc[1][0] = __builtin_amdgcn_mfma_f32_16x16x32_bf16(a1, b0, acc[1][0], 0, 0, 0);
      acc[2][0] = __builtin_amdgcn_mfma_f32_16x16x32_bf16(a2, b0, acc[2][0], 0, 0, 0);
      acc[3][0] = __builtin_amdgcn_mfma_f32_16x16x32_bf16(a3, b0, acc[3][0], 0, 0, 0);
      acc[0][1] = __builtin_amdgcn_mfma_f32_16x16x32_bf16(a0, b1, acc[0][1], 0, 0, 0);
      acc[1][1] = __builtin_amdgcn_mfma_f32_16x16x32_bf16(a1, b1, acc[1][1], 0, 0, 0);
      acc[2][1] = __builtin_amdgcn_mfma_f32_16x16x32_bf16(a2, b1, acc[2][1], 0, 0, 0);
      acc[3][1] = __builtin_amdgcn_mfma_f32_16x16x32_bf16(a3, b1, acc[3][1], 0, 0, 0);
      acc[0][2] = __builtin_amdgcn_mfma_f32_16x16x32_bf16(a0, b2, acc[0][2], 0, 0, 0);
      acc[1][2] = __builtin_amdgcn_mfma_f32_16x16x32_bf16(a1, b2, acc[1][2], 0, 0, 0);
      acc[2][2] = __builtin_amdgcn_mfma_f32_16x16x32_bf16(a2, b2, acc[2][2], 0, 0, 0);
      acc[3][2] = __builtin_amdgcn_mfma_f32_16x16x32_bf16(a3, b2, acc[3][2], 0, 0, 0);
      acc[0][3] = __builtin_amdgcn_mfma_f32_16x16x32_bf16(a0, b3v, acc[0][3], 0, 0, 0);
      acc[1][3] = __builtin_amdgcn_mfma_f32_16x16x32_bf16(a1, b3v, acc[1][3], 0, 0, 0);
      acc[2][3] = __builtin_amdgcn_mfma_f32_16x16x32_bf16(a2, b3v, acc[2][3], 0, 0, 0);
      acc[3][3] = __builtin_amdgcn_mfma_f32_16x16x32_bf16(a3, b3v, acc[3][3], 0, 0, 0);
      // write-late: pack + store next tile to the other buffer
      if (more) {
        char* wb = bs[cur ^ 1];
        *(unsigned*)(wb + wo0) = (unsigned)f2bf(r0[0]) | ((unsigned)f2bf(r1[0]) << 16);
        *(unsigned*)(wb + wo1) = (unsigned)f2bf(r0[1]) | ((unsigned)f2bf(r1[1]) << 16);
        *(unsigned*)(wb + wo2) = (unsigned)f2bf(r0[2]) | ((unsigned)f2bf(r1[2]) << 16);
        *(unsigned*)(wb + wo3) = (unsigned)f2bf(r0[3]) | ((unsigned)f2bf(r1[3]) << 16);
      }
      __syncthreads();
    }
  } else {
    // ---- slow path (last ragged block only): direct guarded loads ----
    for (int k0 = 0; k0 < HIDDEN; k0 += 32) {
      int ka = k0 + l4 * 8;
      bf16x8 a0 = *reinterpret_cast<const bf16x8*>(aP0 + k0);
      bf16x8 a1 = *reinterpret_cast<const bf16x8*>(aP1 + k0);
      bf16x8 a2 = *reinterpret_cast<const bf16x8*>(aP2 + k0);
      bf16x8 a3 = *reinterpret_cast<const bf16x8*>(aP3 + k0);
      const float* pBk = W3 + (size_t)ka * VOCAB;
      #pragma unroll
      for (int ni = 0; ni < 4; ++ni) {
        int col = col0 + ni * 16 + l15;
        bool ok = col < VOCAB;
        const float* pB = pBk + (ok ? col : 0);
        bf16x8 bb;
        #pragma unroll
        for (int j = 0; j < 8; ++j) bb[j] = (short)f2bf(ok ? pB[(size_t)j * VOCAB] : 0.f);
        acc[0][ni] = __builtin_amdgcn_mfma_f32_16x16x32_bf16(a0, bb, acc[0][ni], 0, 0, 0);
        acc[1][ni] = __builtin_amdgcn_mfma_f32_16x16x32_bf16(a1, bb, acc[1][ni], 0, 0, 0);
        acc[2][ni] = __builtin_amdgcn_mfma_f32_16x16x32_bf16(a2, bb, acc[2][ni], 0, 0, 0);
        acc[3][ni] = __builtin_amdgcn_mfma_f32_16x16x32_bf16(a3, bb, acc[3][ni], 0, 0, 0);
      }
    }
  }

  #pragma unroll
  for (int ni = 0; ni < 4; ++ni) {
    int col = col0 + ni * 16 + l15;
    if (col < VOCAB) {
      float bb = b3[col];
      #pragma unroll
      for (int mi = 0; mi < 4; ++mi) {
        #pragma unroll
        for (int r = 0; r < 4; ++r) {
          int row = wrow + mi * 16 + l4 * 4 + r;
          out[(size_t)row * VOCAB + col] = acc[mi][ni][r] + bb;
        }
      }
    }
  }
}

// ---------------------------------------------------------------------------
extern "C" void kernel_launch(void* const* d_in, const int* in_sizes, int n_in,
                              void* d_out, int out_size, void* d_ws, size_t ws_size,
                              hipStream_t stream) {
  const float* ctx     = (const float*)d_in[0];
  const float* embed_w = (const float*)d_in[1];
  const float* W1      = (const float*)d_in[2];
  const float* b1      = (const float*)d_in[3];
  const float* W2      = (const float*)d_in[4];
  const float* b2      = (const float*)d_in[5];
  const float* W3      = (const float*)d_in[6];
  const float* b3      = (const float*)d_in[7];
  float* out = (float*)d_out;

  char* w = (char*)d_ws;
  int*            idx = (int*)w;                         // 8 KB
  float*          val = (float*)(w + 8192);              // 8 KB
  unsigned short* x2  = (unsigned short*)(w + 16384);    // 512 KB

  k_scan<<<BATCH * KCTX / 4, 256, 0, stream>>>(ctx, idx, val);
  k_mlp<<<BATCH / 2, 256, 0, stream>>>(idx, val, embed_w, W1, b1, W2, b2, x2);
  k_l3<<<(VOCAB + 63) / 64, 256, 0, stream>>>((const short*)x2, W3, b3, out);
}